// Round 2
// baseline (125.625 us; speedup 1.0000x reference)
//
#include <hip/hip_runtime.h>
#include <math.h>

// Problem constants (match reference)
#define NXC 1024
#define NYC 1024
#define DC  128
#define NCM1 4
#define NTILE 256   // 16x16 tiles of 64x64, one block each

// ws float offsets (total ~514 KB touched; s never goes to global)
#define WS_ROWP  0        // float2[1024][16] (m,l) row partials -> 32768 float2
#define WS_COLP  65536    // float2[1024][16] (m,l) col partials -> 32768 float2
#define WS_PART  131072   // float2[256] (S0,S1) tile partials

typedef _Float16 half2v __attribute__((ext_vector_type(2)));
union H2U { half2v h; unsigned u; };

#if defined(__has_builtin)
#if __has_builtin(__builtin_amdgcn_fdot2)
#define HAVE_FDOT2 1
#endif
#endif

// ---- replay-safe grid barrier ----------------------------------------------
// State in __device__ globals: zero at module load, self-restoring across
// launches/graph-replays (count returns to 0, gen monotonically increments).
// NOT in d_ws (harness re-poisons ws between iterations).
__device__ unsigned g_bar_count = 0;
__device__ unsigned g_bar_gen   = 0;

__device__ __forceinline__ void grid_barrier(unsigned nblk)
{
    __syncthreads();
    if (threadIdx.x == 0) {
        __threadfence();   // release: make this block's ws writes visible (wb L2)
        unsigned my = __hip_atomic_load(&g_bar_gen, __ATOMIC_RELAXED,
                                        __HIP_MEMORY_SCOPE_AGENT);
        unsigned prev = __hip_atomic_fetch_add(&g_bar_count, 1u,
                                               __ATOMIC_ACQ_REL,
                                               __HIP_MEMORY_SCOPE_AGENT);
        if (prev == nblk - 1u) {
            // last arriver: reset count, then release the new generation
            __hip_atomic_store(&g_bar_count, 0u, __ATOMIC_RELAXED,
                               __HIP_MEMORY_SCOPE_AGENT);
            __hip_atomic_store(&g_bar_gen, my + 1u, __ATOMIC_RELEASE,
                               __HIP_MEMORY_SCOPE_AGENT);
        } else {
            while (__hip_atomic_load(&g_bar_gen, __ATOMIC_ACQUIRE,
                                     __HIP_MEMORY_SCOPE_AGENT) == my) {
                __builtin_amdgcn_s_sleep(2);
            }
        }
        __threadfence();   // acquire: invalidate L1/L2 before reading peers' data
    }
    __syncthreads();
}

// |xa - ya| summed into f32 acc, 8 halves (one 16B chunk) at a time.
__device__ __forceinline__ float absdiff_dot(uint4 xa, uint4 ya, float acc)
{
    const unsigned* xu = (const unsigned*)&xa;
    const unsigned* yu = (const unsigned*)&ya;
    half2v one; one.x = (_Float16)1.f; one.y = (_Float16)1.f;
    #pragma unroll
    for (int q = 0; q < 4; ++q) {
        H2U x, y, d;
        x.u = xu[q]; y.u = yu[q];
        d.h = x.h - y.h;              // v_pk_add_f16 (neg)
        d.u &= 0x7FFF7FFFu;           // packed abs
#ifdef HAVE_FDOT2
        acc = __builtin_amdgcn_fdot2(d.h, one, acc, false);  // v_dot2_f32_f16
#else
        acc += (float)d.h.x + (float)d.h.y;
#endif
    }
    return acc;
}

// -------------------------------------------------------------------------
// Single fused kernel, plain launch. 256 blocks x 512 threads.
// Block = one 64x64 tile. s stays in registers across both grid barriers.
// Phase 1: stage fp16 tiles in LDS (XOR swizzle), compute s (2x4/thread),
//          write per-tile row partials (16/row) and col partials (16/col).
// grid_barrier
// Phase 2: merge 16 partials per row/col (float4 + 3 shuffles), compute
//          dual-softmax weights on register-resident s, one float2/tile.
// grid_barrier
// Block 0: sum 256 tile partials, write 4 logits.
// -------------------------------------------------------------------------
__global__ __launch_bounds__(512, 1) void ssa_fused_kernel(
    const float* __restrict__ zx, const float* __restrict__ zy,
    const float* __restrict__ theta, const float* __restrict__ beta,
    float* __restrict__ ws, float* __restrict__ out)
{
    __shared__ __align__(16) _Float16 xs[64 * 128];   // 16 KB
    __shared__ __align__(16) _Float16 ys[64 * 128];   // 16 KB
    __shared__ float cpm[32][65], cpl[32][65];        // 16.6 KB (padded)
    __shared__ float rm_s[64], rl_s[64], cm_s[64], cl_s[64];
    __shared__ float red0[8], red1[8];

    float* rowp = ws + WS_ROWP;
    float* colp = ws + WS_COLP;
    float* part = ws + WS_PART;

    const int t    = threadIdx.x;
    const int tile = blockIdx.x;
    const int bx   = tile & 15;
    const int by   = tile >> 4;
    const int x0   = by * 64;
    const int y0   = bx * 64;

    // ---- stage x and y: 64 rows x 16 chunks each, 2 chunks/thread ----
    #pragma unroll
    for (int k = 0; k < 2; ++k) {
        int idx = t + k * 512;
        int r   = idx >> 4;
        int j   = idx & 15;
        int off = r * 128 + 8 * (j ^ ((r >> 2) & 7));
        const float4* gx = (const float4*)(zx + (size_t)(x0 + r) * DC + 8 * j);
        float4 v0 = gx[0], v1 = gx[1];
        uint4 hx;
        {
            H2U a, b, c, d;
            a.h.x = (_Float16)v0.x; a.h.y = (_Float16)v0.y;
            b.h.x = (_Float16)v0.z; b.h.y = (_Float16)v0.w;
            c.h.x = (_Float16)v1.x; c.h.y = (_Float16)v1.y;
            d.h.x = (_Float16)v1.z; d.h.y = (_Float16)v1.w;
            hx.x = a.u; hx.y = b.u; hx.z = c.u; hx.w = d.u;
        }
        *(uint4*)(xs + off) = hx;
    }
    #pragma unroll
    for (int k = 0; k < 2; ++k) {
        int idx = t + k * 512;
        int r   = idx >> 4;
        int j   = idx & 15;
        int off = r * 128 + 8 * (j ^ ((r >> 2) & 7));
        const float4* gy = (const float4*)(zy + (size_t)(y0 + r) * DC + 8 * j);
        float4 v0 = gy[0], v1 = gy[1];
        uint4 hy;
        {
            H2U a, b, c, d;
            a.h.x = (_Float16)v0.x; a.h.y = (_Float16)v0.y;
            b.h.x = (_Float16)v0.z; b.h.y = (_Float16)v0.w;
            c.h.x = (_Float16)v1.x; c.h.y = (_Float16)v1.y;
            d.h.x = (_Float16)v1.z; d.h.y = (_Float16)v1.w;
            hy.x = a.u; hy.y = b.u; hy.z = c.u; hy.w = d.u;
        }
        *(uint4*)(ys + off) = hy;
    }
    __syncthreads();

    const int tx = t & 15;            // 4 cols each (64 cols)
    const int ty = t >> 4;            // 0..31, 2 rows each (64 rows)
    const int xswz = (ty >> 1) & 7;   // matches store swizzle for rows 2ty,2ty+1
    const int yswz = tx & 7;          // matches store swizzle for rows 4tx..4tx+3

    const _Float16* xb = xs + (2 * ty) * 128;
    const _Float16* yb = ys + (4 * tx) * 128;

    // ---- 2x4 micro-tile L1 distances, rolling prefetch ----
    float acc[2][4];
    #pragma unroll
    for (int i = 0; i < 2; ++i)
        #pragma unroll
        for (int j = 0; j < 4; ++j) acc[i][j] = 0.f;

    uint4 xc0 = *(const uint4*)(xb +       8 * (0 ^ xswz));
    uint4 xc1 = *(const uint4*)(xb + 128 + 8 * (0 ^ xswz));
    uint4 yc0 = *(const uint4*)(yb +       8 * (0 ^ yswz));
    uint4 yc1 = *(const uint4*)(yb + 128 + 8 * (0 ^ yswz));
    uint4 yc2 = *(const uint4*)(yb + 256 + 8 * (0 ^ yswz));
    uint4 yc3 = *(const uint4*)(yb + 384 + 8 * (0 ^ yswz));

    #pragma unroll 4
    for (int j = 0; j < 16; ++j) {
        uint4 xa0 = xc0, xa1 = xc1, ya0 = yc0, ya1 = yc1, ya2 = yc2, ya3 = yc3;
        const int jn = (j + 1) & 15;
        xc0 = *(const uint4*)(xb +       8 * (jn ^ xswz));
        xc1 = *(const uint4*)(xb + 128 + 8 * (jn ^ xswz));
        yc0 = *(const uint4*)(yb +       8 * (jn ^ yswz));
        yc1 = *(const uint4*)(yb + 128 + 8 * (jn ^ yswz));
        yc2 = *(const uint4*)(yb + 256 + 8 * (jn ^ yswz));
        yc3 = *(const uint4*)(yb + 384 + 8 * (jn ^ yswz));

        acc[0][0] = absdiff_dot(xa0, ya0, acc[0][0]);
        acc[0][1] = absdiff_dot(xa0, ya1, acc[0][1]);
        acc[0][2] = absdiff_dot(xa0, ya2, acc[0][2]);
        acc[0][3] = absdiff_dot(xa0, ya3, acc[0][3]);
        acc[1][0] = absdiff_dot(xa1, ya0, acc[1][0]);
        acc[1][1] = absdiff_dot(xa1, ya1, acc[1][1]);
        acc[1][2] = absdiff_dot(xa1, ya2, acc[1][2]);
        acc[1][3] = absdiff_dot(xa1, ya3, acc[1][3]);
    }

    float sv[2][4];
    #pragma unroll
    for (int i = 0; i < 2; ++i)
        #pragma unroll
        for (int j = 0; j < 4; ++j) sv[i][j] = -acc[i][j];

    // ---- per-tile ROW partials: merge 4 cols, then across 16 tx lanes ----
    #pragma unroll
    for (int i = 0; i < 2; ++i) {
        float m = fmaxf(fmaxf(sv[i][0], sv[i][1]), fmaxf(sv[i][2], sv[i][3]));
        float l = __expf(sv[i][0] - m) + __expf(sv[i][1] - m)
                + __expf(sv[i][2] - m) + __expf(sv[i][3] - m);
        #pragma unroll
        for (int off = 1; off < 16; off <<= 1) {
            float mo = __shfl_xor(m, off, 64);
            float lo = __shfl_xor(l, off, 64);
            float nm = fmaxf(m, mo);
            l = l * __expf(m - nm) + lo * __expf(mo - nm);
            m = nm;
        }
        if (tx == 0)
            *(float2*)(rowp + 2 * ((size_t)(x0 + 2 * ty + i) * 16 + bx)) = make_float2(m, l);
    }

    // ---- per-tile COL partials (merge the 32 ty entries via LDS) ----
    #pragma unroll
    for (int j = 0; j < 4; ++j) {
        float m = fmaxf(sv[0][j], sv[1][j]);
        float l = __expf(sv[0][j] - m) + __expf(sv[1][j] - m);
        cpm[ty][4 * tx + j] = m;
        cpl[ty][4 * tx + j] = l;
    }
    __syncthreads();
    if (t < 64) {
        float m = cpm[0][t], l = cpl[0][t];
        #pragma unroll 8
        for (int k = 1; k < 32; ++k) {
            float mo = cpm[k][t], lo = cpl[k][t];
            float nm = fmaxf(m, mo);
            l = l * __expf(m - nm) + lo * __expf(mo - nm);
            m = nm;
        }
        *(float2*)(colp + 2 * ((size_t)(y0 + t) * 16 + by)) = make_float2(m, l);
    }

    grid_barrier(NTILE);

    // ---- phase 2: merge 16 row / 16 col partials per line (8 lanes/line) ----
    const int item  = t >> 3;        // 0..63
    const int lane8 = t & 7;
    {
        float4 q = ((const float4*)rowp)[(size_t)(x0 + item) * 8 + lane8];
        float m = fmaxf(q.x, q.z);
        float l = q.y * __expf(q.x - m) + q.w * __expf(q.z - m);
        #pragma unroll
        for (int off = 1; off < 8; off <<= 1) {
            float mo = __shfl_xor(m, off, 64);
            float lo = __shfl_xor(l, off, 64);
            float nm = fmaxf(m, mo);
            l = l * __expf(m - nm) + lo * __expf(mo - nm);
            m = nm;
        }
        if (lane8 == 0) { rm_s[item] = m; rl_s[item] = 1.f / l; }
    }
    {
        float4 q = ((const float4*)colp)[(size_t)(y0 + item) * 8 + lane8];
        float m = fmaxf(q.x, q.z);
        float l = q.y * __expf(q.x - m) + q.w * __expf(q.z - m);
        #pragma unroll
        for (int off = 1; off < 8; off <<= 1) {
            float mo = __shfl_xor(m, off, 64);
            float lo = __shfl_xor(l, off, 64);
            float nm = fmaxf(m, mo);
            l = l * __expf(m - nm) + lo * __expf(mo - nm);
            m = nm;
        }
        if (lane8 == 0) { cm_s[item] = m; cl_s[item] = 1.f / l; }
    }
    __syncthreads();

    // ---- dual-softmax weights on register-resident s, accumulate S0/S1 ----
    float S0 = 0.f, S1 = 0.f;
    #pragma unroll
    for (int i = 0; i < 2; ++i) {
        const float rm = rm_s[2 * ty + i];
        const float rl = rl_s[2 * ty + i];
        #pragma unroll
        for (int j = 0; j < 4; ++j) {
            const float cm = cm_s[4 * tx + j];
            const float cl = cl_s[4 * tx + j];
            float s = sv[i][j];
            float a = __expf(s - rm) * rl;
            float b = __expf(s - cm) * cl;
            float w = a + b - a * b;
            S0 += w;
            S1 += w * s;
        }
    }
    #pragma unroll
    for (int off = 32; off; off >>= 1) {
        S0 += __shfl_xor(S0, off, 64);
        S1 += __shfl_xor(S1, off, 64);
    }
    if ((t & 63) == 0) { red0[t >> 6] = S0; red1[t >> 6] = S1; }
    __syncthreads();
    if (t == 0) {
        float t0 = 0.f, t1 = 0.f;
        #pragma unroll
        for (int w = 0; w < 8; ++w) { t0 += red0[w]; t1 += red1[w]; }
        *(float2*)(part + 2 * tile) = make_float2(t0, t1);
    }

    grid_barrier(NTILE);

    // ---- block 0: sum 256 tile partials, write the 4 logits ----
    if (blockIdx.x == 0) {
        float P0 = 0.f, P1 = 0.f;
        if (t < NTILE) {
            float2 p = ((const float2*)part)[t];
            P0 = p.x; P1 = p.y;
        }
        #pragma unroll
        for (int off = 32; off; off >>= 1) {
            P0 += __shfl_xor(P0, off, 64);
            P1 += __shfl_xor(P1, off, 64);
        }
        if ((t & 63) == 0) { red0[t >> 6] = P0; red1[t >> 6] = P1; }
        __syncthreads();
        if (t < NCM1) {
            float t0 = 0.f, t1 = 0.f;
            #pragma unroll
            for (int w = 0; w < 8; ++w) { t0 += red0[w]; t1 += red1[w]; }
            float c = t1 / t0;
            out[t] = c * theta[t] + beta[t];
        }
    }
}

// -------------------------------------------------------------------------
extern "C" void kernel_launch(void* const* d_in, const int* in_sizes, int n_in,
                              void* d_out, int out_size, void* d_ws, size_t ws_size,
                              hipStream_t stream)
{
    const float* zx    = (const float*)d_in[0];
    const float* zy    = (const float*)d_in[1];
    const float* theta = (const float*)d_in[2];
    const float* beta  = (const float*)d_in[3];
    float* out = (float*)d_out;
    float* ws  = (float*)d_ws;

    ssa_fused_kernel<<<NTILE, 512, 0, stream>>>(zx, zy, theta, beta, ws, out);
}

// Round 3
// 75.365 us; speedup vs baseline: 1.6669x; 1.6669x over previous
//
#include <hip/hip_runtime.h>
#include <math.h>

// Problem constants (match reference)
#define NXC 1024
#define NYC 1024
#define DC  128
#define NCM1 4
#define NTILE 256   // 16x16 tiles of 64x64, one block each

// ws float offsets
#define WS_ROWP  0        // float2[1024][16] (m,l) row partials
#define WS_COLP  65536    // float2[1024][16] (m,l) col partials
#define WS_PART  131072   // float2[256] (S0,S1) tile partials

typedef _Float16 half2v __attribute__((ext_vector_type(2)));
union H2U { half2v h; unsigned u; };
union F2U { float2 f; unsigned long long u; };

#if defined(__has_builtin)
#if __has_builtin(__builtin_amdgcn_fdot2)
#define HAVE_FDOT2 1
#endif
#endif

// ---- sync state in __device__ globals --------------------------------------
// Zero at module load; self-restoring each launch (last block resets), so
// correct across graph replays. NOT in d_ws (harness re-poisons ws).
// One counter per 64B line to avoid cross-XCD line ping-pong.
__device__ unsigned g_rowdone[16 * 16];
__device__ unsigned g_coldone[16 * 16];
__device__ unsigned g_done = 0;

// Agent-scope relaxed atomics: sc0/sc1 coherent accesses, NO buffer_inv /
// buffer_wbl2 cache maintenance (that was the 64us stall in the previous
// version: acquire-spin = L2 invalidate per poll x 256 CUs).
__device__ __forceinline__ void st_agent_f2(float* p, float2 v) {
    F2U u; u.f = v;
    __hip_atomic_store((unsigned long long*)p, u.u, __ATOMIC_RELAXED,
                       __HIP_MEMORY_SCOPE_AGENT);
}
__device__ __forceinline__ float2 ld_agent_f2(const float* p) {
    F2U u;
    u.u = __hip_atomic_load((const unsigned long long*)p, __ATOMIC_RELAXED,
                            __HIP_MEMORY_SCOPE_AGENT);
    return u.f;
}
__device__ __forceinline__ unsigned ld_agent_u32(const unsigned* p) {
    return __hip_atomic_load(p, __ATOMIC_RELAXED, __HIP_MEMORY_SCOPE_AGENT);
}

// |xa - ya| summed into f32 acc, 8 halves (one 16B chunk) at a time.
__device__ __forceinline__ float absdiff_dot(uint4 xa, uint4 ya, float acc)
{
    const unsigned* xu = (const unsigned*)&xa;
    const unsigned* yu = (const unsigned*)&ya;
    half2v one; one.x = (_Float16)1.f; one.y = (_Float16)1.f;
    #pragma unroll
    for (int q = 0; q < 4; ++q) {
        H2U x, y, d;
        x.u = xu[q]; y.u = yu[q];
        d.h = x.h - y.h;              // v_pk_add_f16 (neg)
        d.u &= 0x7FFF7FFFu;           // packed abs
#ifdef HAVE_FDOT2
        acc = __builtin_amdgcn_fdot2(d.h, one, acc, false);  // v_dot2_f32_f16
#else
        acc += (float)d.h.x + (float)d.h.y;
#endif
    }
    return acc;
}

// -------------------------------------------------------------------------
// Single fused kernel, plain launch. 256 blocks x 512 threads, 1 block/CU.
// Block = one 64x64 tile; s stays in registers throughout.
// Phase 1: stage fp16 tiles in LDS (XOR swizzle), compute s (2x4/thread),
//          publish per-tile row/col (m,l) partials via sc1 atomic stores,
//          then bump rowdone[by] / coldone[bx] (relaxed; __syncthreads
//          already drained vmcnt so the data stores are at the coherence
//          point before the flag increment).
// Wait: only rowdone[by]==16 && coldone[bx]==16 (31 peers, not 255).
// Phase 2: merge 16 partials per row/col, dual-softmax weights on the
//          register-resident s, one float2 partial per tile.
// Last block (done counter) reduces 256 partials, writes logits, resets.
// -------------------------------------------------------------------------
__global__ __launch_bounds__(512, 1) void ssa_fused_kernel(
    const float* __restrict__ zx, const float* __restrict__ zy,
    const float* __restrict__ theta, const float* __restrict__ beta,
    float* __restrict__ ws, float* __restrict__ out)
{
    __shared__ __align__(16) _Float16 xs[64 * 128];   // 16 KB
    __shared__ __align__(16) _Float16 ys[64 * 128];   // 16 KB
    __shared__ float cpm[32][65], cpl[32][65];        // 16.6 KB (padded)
    __shared__ float rm_s[64], rl_s[64], cm_s[64], cl_s[64];
    __shared__ float red0[8], red1[8];
    __shared__ unsigned last_flag;

    float* rowp = ws + WS_ROWP;
    float* colp = ws + WS_COLP;
    float* part = ws + WS_PART;

    const int t    = threadIdx.x;
    const int tile = blockIdx.x;
    const int bx   = tile & 15;
    const int by   = tile >> 4;
    const int x0   = by * 64;
    const int y0   = bx * 64;

    // ---- stage x and y: 64 rows x 16 chunks each, 2 chunks/thread ----
    #pragma unroll
    for (int k = 0; k < 2; ++k) {
        int idx = t + k * 512;
        int r   = idx >> 4;
        int j   = idx & 15;
        int off = r * 128 + 8 * (j ^ ((r >> 2) & 7));
        const float4* gx = (const float4*)(zx + (size_t)(x0 + r) * DC + 8 * j);
        float4 v0 = gx[0], v1 = gx[1];
        uint4 hx;
        {
            H2U a, b, c, d;
            a.h.x = (_Float16)v0.x; a.h.y = (_Float16)v0.y;
            b.h.x = (_Float16)v0.z; b.h.y = (_Float16)v0.w;
            c.h.x = (_Float16)v1.x; c.h.y = (_Float16)v1.y;
            d.h.x = (_Float16)v1.z; d.h.y = (_Float16)v1.w;
            hx.x = a.u; hx.y = b.u; hx.z = c.u; hx.w = d.u;
        }
        *(uint4*)(xs + off) = hx;
    }
    #pragma unroll
    for (int k = 0; k < 2; ++k) {
        int idx = t + k * 512;
        int r   = idx >> 4;
        int j   = idx & 15;
        int off = r * 128 + 8 * (j ^ ((r >> 2) & 7));
        const float4* gy = (const float4*)(zy + (size_t)(y0 + r) * DC + 8 * j);
        float4 v0 = gy[0], v1 = gy[1];
        uint4 hy;
        {
            H2U a, b, c, d;
            a.h.x = (_Float16)v0.x; a.h.y = (_Float16)v0.y;
            b.h.x = (_Float16)v0.z; b.h.y = (_Float16)v0.w;
            c.h.x = (_Float16)v1.x; c.h.y = (_Float16)v1.y;
            d.h.x = (_Float16)v1.z; d.h.y = (_Float16)v1.w;
            hy.x = a.u; hy.y = b.u; hy.z = c.u; hy.w = d.u;
        }
        *(uint4*)(ys + off) = hy;
    }
    __syncthreads();

    const int tx = t & 15;            // 4 cols each (64 cols)
    const int ty = t >> 4;            // 0..31, 2 rows each (64 rows)
    const int xswz = (ty >> 1) & 7;
    const int yswz = tx & 7;

    const _Float16* xb = xs + (2 * ty) * 128;
    const _Float16* yb = ys + (4 * tx) * 128;

    // ---- 2x4 micro-tile L1 distances, rolling prefetch ----
    float acc[2][4];
    #pragma unroll
    for (int i = 0; i < 2; ++i)
        #pragma unroll
        for (int j = 0; j < 4; ++j) acc[i][j] = 0.f;

    uint4 xc0 = *(const uint4*)(xb +       8 * (0 ^ xswz));
    uint4 xc1 = *(const uint4*)(xb + 128 + 8 * (0 ^ xswz));
    uint4 yc0 = *(const uint4*)(yb +       8 * (0 ^ yswz));
    uint4 yc1 = *(const uint4*)(yb + 128 + 8 * (0 ^ yswz));
    uint4 yc2 = *(const uint4*)(yb + 256 + 8 * (0 ^ yswz));
    uint4 yc3 = *(const uint4*)(yb + 384 + 8 * (0 ^ yswz));

    #pragma unroll 4
    for (int j = 0; j < 16; ++j) {
        uint4 xa0 = xc0, xa1 = xc1, ya0 = yc0, ya1 = yc1, ya2 = yc2, ya3 = yc3;
        const int jn = (j + 1) & 15;
        xc0 = *(const uint4*)(xb +       8 * (jn ^ xswz));
        xc1 = *(const uint4*)(xb + 128 + 8 * (jn ^ xswz));
        yc0 = *(const uint4*)(yb +       8 * (jn ^ yswz));
        yc1 = *(const uint4*)(yb + 128 + 8 * (jn ^ yswz));
        yc2 = *(const uint4*)(yb + 256 + 8 * (jn ^ yswz));
        yc3 = *(const uint4*)(yb + 384 + 8 * (jn ^ yswz));

        acc[0][0] = absdiff_dot(xa0, ya0, acc[0][0]);
        acc[0][1] = absdiff_dot(xa0, ya1, acc[0][1]);
        acc[0][2] = absdiff_dot(xa0, ya2, acc[0][2]);
        acc[0][3] = absdiff_dot(xa0, ya3, acc[0][3]);
        acc[1][0] = absdiff_dot(xa1, ya0, acc[1][0]);
        acc[1][1] = absdiff_dot(xa1, ya1, acc[1][1]);
        acc[1][2] = absdiff_dot(xa1, ya2, acc[1][2]);
        acc[1][3] = absdiff_dot(xa1, ya3, acc[1][3]);
    }

    float sv[2][4];
    #pragma unroll
    for (int i = 0; i < 2; ++i)
        #pragma unroll
        for (int j = 0; j < 4; ++j) sv[i][j] = -acc[i][j];

    // ---- per-tile ROW partials: merge 4 cols, then across 16 tx lanes ----
    #pragma unroll
    for (int i = 0; i < 2; ++i) {
        float m = fmaxf(fmaxf(sv[i][0], sv[i][1]), fmaxf(sv[i][2], sv[i][3]));
        float l = __expf(sv[i][0] - m) + __expf(sv[i][1] - m)
                + __expf(sv[i][2] - m) + __expf(sv[i][3] - m);
        #pragma unroll
        for (int off = 1; off < 16; off <<= 1) {
            float mo = __shfl_xor(m, off, 64);
            float lo = __shfl_xor(l, off, 64);
            float nm = fmaxf(m, mo);
            l = l * __expf(m - nm) + lo * __expf(mo - nm);
            m = nm;
        }
        if (tx == 0)
            st_agent_f2(rowp + 2 * ((size_t)(x0 + 2 * ty + i) * 16 + bx),
                        make_float2(m, l));
    }

    // ---- per-tile COL partials (merge the 32 ty entries via LDS) ----
    #pragma unroll
    for (int j = 0; j < 4; ++j) {
        float m = fmaxf(sv[0][j], sv[1][j]);
        float l = __expf(sv[0][j] - m) + __expf(sv[1][j] - m);
        cpm[ty][4 * tx + j] = m;
        cpl[ty][4 * tx + j] = l;
    }
    __syncthreads();
    if (t < 64) {
        float m = cpm[0][t], l = cpl[0][t];
        #pragma unroll 8
        for (int k = 1; k < 32; ++k) {
            float mo = cpm[k][t], lo = cpl[k][t];
            float nm = fmaxf(m, mo);
            l = l * __expf(m - nm) + lo * __expf(mo - nm);
            m = nm;
        }
        st_agent_f2(colp + 2 * ((size_t)(y0 + t) * 16 + by), make_float2(m, l));
    }

    // __syncthreads drains vmcnt(0): all sc1 data stores are at the
    // coherence point before the flag increments below.
    __syncthreads();
    if (t == 0) {
        __hip_atomic_fetch_add(&g_rowdone[by * 16], 1u, __ATOMIC_RELAXED,
                               __HIP_MEMORY_SCOPE_AGENT);
        __hip_atomic_fetch_add(&g_coldone[bx * 16], 1u, __ATOMIC_RELAXED,
                               __HIP_MEMORY_SCOPE_AGENT);
        // wait only for our tile-row and tile-column groups (31 peers)
        while (ld_agent_u32(&g_rowdone[by * 16]) < 16u)
            __builtin_amdgcn_s_sleep(8);
        while (ld_agent_u32(&g_coldone[bx * 16]) < 16u)
            __builtin_amdgcn_s_sleep(8);
    }
    __syncthreads();

    // ---- phase 2: merge 16 row / 16 col partials per line (8 lanes/line) ----
    const int item  = t >> 3;        // 0..63
    const int lane8 = t & 7;
    {
        float2 e0 = ld_agent_f2(rowp + 2 * ((size_t)(x0 + item) * 16 + 2 * lane8));
        float2 e1 = ld_agent_f2(rowp + 2 * ((size_t)(x0 + item) * 16 + 2 * lane8 + 1));
        float m = fmaxf(e0.x, e1.x);
        float l = e0.y * __expf(e0.x - m) + e1.y * __expf(e1.x - m);
        #pragma unroll
        for (int off = 1; off < 8; off <<= 1) {
            float mo = __shfl_xor(m, off, 64);
            float lo = __shfl_xor(l, off, 64);
            float nm = fmaxf(m, mo);
            l = l * __expf(m - nm) + lo * __expf(mo - nm);
            m = nm;
        }
        if (lane8 == 0) { rm_s[item] = m; rl_s[item] = 1.f / l; }
    }
    {
        float2 e0 = ld_agent_f2(colp + 2 * ((size_t)(y0 + item) * 16 + 2 * lane8));
        float2 e1 = ld_agent_f2(colp + 2 * ((size_t)(y0 + item) * 16 + 2 * lane8 + 1));
        float m = fmaxf(e0.x, e1.x);
        float l = e0.y * __expf(e0.x - m) + e1.y * __expf(e1.x - m);
        #pragma unroll
        for (int off = 1; off < 8; off <<= 1) {
            float mo = __shfl_xor(m, off, 64);
            float lo = __shfl_xor(l, off, 64);
            float nm = fmaxf(m, mo);
            l = l * __expf(m - nm) + lo * __expf(mo - nm);
            m = nm;
        }
        if (lane8 == 0) { cm_s[item] = m; cl_s[item] = 1.f / l; }
    }
    __syncthreads();

    // ---- dual-softmax weights on register-resident s, accumulate S0/S1 ----
    float S0 = 0.f, S1 = 0.f;
    #pragma unroll
    for (int i = 0; i < 2; ++i) {
        const float rm = rm_s[2 * ty + i];
        const float rl = rl_s[2 * ty + i];
        #pragma unroll
        for (int j = 0; j < 4; ++j) {
            const float cm = cm_s[4 * tx + j];
            const float cl = cl_s[4 * tx + j];
            float s = sv[i][j];
            float a = __expf(s - rm) * rl;
            float b = __expf(s - cm) * cl;
            float w = a + b - a * b;
            S0 += w;
            S1 += w * s;
        }
    }
    #pragma unroll
    for (int off = 32; off; off >>= 1) {
        S0 += __shfl_xor(S0, off, 64);
        S1 += __shfl_xor(S1, off, 64);
    }
    if ((t & 63) == 0) { red0[t >> 6] = S0; red1[t >> 6] = S1; }
    __syncthreads();
    if (t == 0) {
        float t0 = 0.f, t1 = 0.f;
        #pragma unroll
        for (int w = 0; w < 8; ++w) { t0 += red0[w]; t1 += red1[w]; }
        st_agent_f2(part + 2 * tile, make_float2(t0, t1));
    }

    // drain part store, then bump done; 256th block does the final reduce
    __syncthreads();
    if (t == 0) {
        unsigned prev = __hip_atomic_fetch_add(&g_done, 1u, __ATOMIC_RELAXED,
                                               __HIP_MEMORY_SCOPE_AGENT);
        last_flag = (prev == NTILE - 1u) ? 1u : 0u;
    }
    __syncthreads();

    if (last_flag) {
        float P0 = 0.f, P1 = 0.f;
        if (t < NTILE) {
            float2 p = ld_agent_f2(part + 2 * t);
            P0 = p.x; P1 = p.y;
        }
        #pragma unroll
        for (int off = 32; off; off >>= 1) {
            P0 += __shfl_xor(P0, off, 64);
            P1 += __shfl_xor(P1, off, 64);
        }
        if ((t & 63) == 0) { red0[t >> 6] = P0; red1[t >> 6] = P1; }
        // reset sync state for the next launch / graph replay
        if (t < 16) {
            __hip_atomic_store(&g_rowdone[t * 16], 0u, __ATOMIC_RELAXED,
                               __HIP_MEMORY_SCOPE_AGENT);
            __hip_atomic_store(&g_coldone[t * 16], 0u, __ATOMIC_RELAXED,
                               __HIP_MEMORY_SCOPE_AGENT);
        }
        if (t == 16)
            __hip_atomic_store(&g_done, 0u, __ATOMIC_RELAXED,
                               __HIP_MEMORY_SCOPE_AGENT);
        __syncthreads();
        if (t < NCM1) {
            float t0 = 0.f, t1 = 0.f;
            #pragma unroll
            for (int w = 0; w < 8; ++w) { t0 += red0[w]; t1 += red1[w]; }
            float c = t1 / t0;
            out[t] = c * theta[t] + beta[t];
        }
    }
}

// -------------------------------------------------------------------------
extern "C" void kernel_launch(void* const* d_in, const int* in_sizes, int n_in,
                              void* d_out, int out_size, void* d_ws, size_t ws_size,
                              hipStream_t stream)
{
    const float* zx    = (const float*)d_in[0];
    const float* zy    = (const float*)d_in[1];
    const float* theta = (const float*)d_in[2];
    const float* beta  = (const float*)d_in[3];
    float* out = (float*)d_out;
    float* ws  = (float*)d_ws;

    ssa_fused_kernel<<<NTILE, 512, 0, stream>>>(zx, zy, theta, beta, ws, out);
}